// Round 5
// baseline (781.488 us; speedup 1.0000x reference)
//
#include <hip/hip_runtime.h>
#include <math.h>

// ContinuousFilterConv, round 10: revert R9's pairing (scratch-spill
// regression: VGPR 84->64, FETCH +205MB, WRITE +130MB => spills), restore
// the R8 MLP kernel byte-for-byte (194us proven). New in R10: the entire
// aux pipeline (out-zero + hist + pack_w + scan + perm) fused into ONE
// 512-block kernel with a device-scope generation grid-barrier (512 = 2
// blocks/CU guaranteed co-resident). Dispatches: 8 -> 4 (memset, aux_mega,
// edge_mlp, finalize). Cross-XCD visibility: __syncthreads() drains vmcnt
// before arrival; __threadfence() (agent fence: L2 wb+inv) on both sides
// of the barrier (Guideline 16).

#define TE 64
#define HID 64
#define NBLK_MLP 768
#define NBLK_AUX 512

typedef __attribute__((ext_vector_type(8))) short short8;
typedef __attribute__((ext_vector_type(4))) float float4v;

__device__ __forceinline__ float fast_tanh(float x) {
    float t = __expf(2.0f * x);
    return 1.0f - 2.0f * __builtin_amdgcn_rcpf(t + 1.0f);
}

__device__ __forceinline__ void split_bf16(float x, unsigned short& hi,
                                           unsigned short& lo) {
    unsigned b = __float_as_uint(x);
    hi = (unsigned short)(b >> 16);
    float hf = __uint_as_float(b & 0xffff0000u);
    lo = (unsigned short)(__float_as_uint(x - hf) >> 16);
}

__device__ __forceinline__ void split8(const float4 u0, const float4 u1,
                                       short8& h, short8& l) {
    float xv[8] = {u0.x, u0.y, u0.z, u0.w, u1.x, u1.y, u1.z, u1.w};
    #pragma unroll
    for (int j = 0; j < 8; ++j) {
        unsigned short hi, lo;
        split_bf16(xv[j], hi, lo);
        h[j] = (short)hi; l[j] = (short)lo;
    }
}

// lgkm-only barrier: LDS ordering without draining global loads/stores.
__device__ __forceinline__ void bar_lgkm() {
    asm volatile("s_waitcnt lgkmcnt(0)" ::: "memory");
    __builtin_amdgcn_sched_barrier(0);
    __builtin_amdgcn_s_barrier();
    __builtin_amdgcn_sched_barrier(0);
}

// Device-scope generation grid barrier. Requires all gridDim.x blocks
// co-resident (NBLK_AUX=512 = 2/CU on 256 CUs -- large slack vs 3/CU cap).
// __syncthreads() has vmcnt(0)-drain semantics, so all block stores are in
// L2 before thread 0 fences (wbl2) and arrives.
__device__ __forceinline__ void gbar(int* cnt, int* gen, int nblk) {
    __syncthreads();
    if (threadIdx.x == 0) {
        __threadfence();
        int g = __hip_atomic_load(gen, __ATOMIC_RELAXED, __HIP_MEMORY_SCOPE_AGENT);
        int a = __hip_atomic_fetch_add(cnt, 1, __ATOMIC_ACQ_REL, __HIP_MEMORY_SCOPE_AGENT);
        if (a == nblk - 1) {
            __hip_atomic_store(cnt, 0, __ATOMIC_RELAXED, __HIP_MEMORY_SCOPE_AGENT);
            __hip_atomic_store(gen, g + 1, __ATOMIC_RELEASE, __HIP_MEMORY_SCOPE_AGENT);
        } else {
            while (__hip_atomic_load(gen, __ATOMIC_ACQUIRE, __HIP_MEMORY_SCOPE_AGENT) == g)
                __builtin_amdgcn_s_sleep(2);
        }
        __threadfence();
    }
    __syncthreads();
}

// Segmentation scan for one 64-edge tile (wave-redundant, lane <-> edge).
__device__ __forceinline__ void tile_scan(int2 pr, int lane, int w, int q,
    int& M_head, int& M_sidx, int& M_d, int& M_nseg,
    int* M_seg, int* M_src)
{
    int d = pr.x, s = pr.y;
    int dprev = __shfl_up(d, 1);
    M_head = (lane == 0 || dprev != d) ? 1 : 0;
    int sv = M_head;
    #pragma unroll
    for (int m = 1; m < 64; m <<= 1) {
        int y = __shfl_up(sv, m);
        if (lane >= m) sv += y;
    }
    M_sidx = sv - 1;
    M_d = d;
    M_nseg = __shfl(sv, 63);
    #pragma unroll
    for (int r = 0; r < 4; ++r) {
        int el = w * 16 + q * 4 + r;
        M_seg[r] = __shfl(M_sidx, el);
        M_src[r] = __shfl(s, el);
    }
}

// ---------------- fused aux: out-zero + hist + pack_w + scan + perm ----------
// B frag for 16x16x32: lane(q,n) holds B[k=ks*32+q*8+j][f=nt*16+n], j=0..7.
// Linear: chunk = (nt*2+ks)*64 + q*16 + n, elem = chunk*8 + j.
// wpack: [W1h 4096][W1l 4096][W2h 4096][W2l 4096] u16.
__global__ __launch_bounds__(256) void aux_mega(
    const int2* __restrict__ edge_list, int* __restrict__ cursor,
    int* __restrict__ blocksums, int* __restrict__ bar,   // bar[0]=cnt bar[1]=gen
    int* __restrict__ perm, int E, int N,
    const float* __restrict__ W1, const float* __restrict__ W2,
    unsigned short* __restrict__ wpack,
    float4* __restrict__ out4, int n4)
{
    __shared__ int wsumI[4];
    const int t = threadIdx.x;
    const int lane = t & 63, wv = t >> 6;
    const int G = gridDim.x * 256;
    const int gid = blockIdx.x * 256 + t;
    const int nblk = gridDim.x;

    // ---- P0: zero out, histogram, pack W ----
    for (int i = gid; i < n4; i += G) out4[i] = (float4){0.f, 0.f, 0.f, 0.f};
    for (int i = gid; i < E; i += G) atomicAdd(&cursor[edge_list[i].x], 1);
    if (gid < 4096) {
        int idx = gid;
        int k = idx >> 6, f = idx & 63;
        int nt = f >> 4, n = f & 15, ks = k >> 5, q = (k >> 3) & 3, j = k & 7;
        int fi = (((nt * 2 + ks) * 4 + q) * 16 + n) * 8 + j;
        unsigned short hi, lo;
        split_bf16(W1[idx], hi, lo);
        wpack[fi] = hi; wpack[4096 + fi] = lo;
        split_bf16(W2[idx], hi, lo);
        wpack[8192 + fi] = hi; wpack[12288 + fi] = lo;
    }
    gbar(bar, bar + 1, nblk);

    // ---- P1a: per-chunk (1024 ints) local exclusive scan ----
    const int nchunks = (N + 1023) >> 10;          // 49 for N=50000
    if ((int)blockIdx.x < nchunks) {
        int base = blockIdx.x * 1024 + t * 4;
        int x0 = 0, x1 = 0, x2 = 0, x3 = 0;
        if (base + 3 < N) {
            int4 v4 = *(const int4*)&cursor[base];
            x0 = v4.x; x1 = v4.y; x2 = v4.z; x3 = v4.w;
        } else {
            if (base     < N) x0 = cursor[base];
            if (base + 1 < N) x1 = cursor[base + 1];
            if (base + 2 < N) x2 = cursor[base + 2];
            if (base + 3 < N) x3 = cursor[base + 3];
        }
        int s = x0 + x1 + x2 + x3;
        int v = s;
        #pragma unroll
        for (int dd = 1; dd < 64; dd <<= 1) {
            int y = __shfl_up(v, dd);
            if (lane >= dd) v += y;
        }
        if (lane == 63) wsumI[wv] = v;
        __syncthreads();
        int w0 = wsumI[0], w1 = wsumI[1], w2 = wsumI[2], w3 = wsumI[3];
        int woff = (wv == 0) ? 0 : (wv == 1) ? w0 : (wv == 2) ? w0 + w1
                                                             : w0 + w1 + w2;
        int excl = woff + v - s;
        if (base     < N) cursor[base]     = excl;
        if (base + 1 < N) cursor[base + 1] = excl + x0;
        if (base + 2 < N) cursor[base + 2] = excl + x0 + x1;
        if (base + 3 < N) cursor[base + 3] = excl + x0 + x1 + x2;
        if (t == 0) blocksums[blockIdx.x] = w0 + w1 + w2 + w3;
    }
    gbar(bar, bar + 1, nblk);

    // ---- P1b: single-wave exclusive scan of chunk sums ----
    if (blockIdx.x == 0 && wv == 0) {
        int x = (lane < nchunks) ? blocksums[lane] : 0;
        int v = x;
        #pragma unroll
        for (int dd = 1; dd < 64; dd <<= 1) {
            int y = __shfl_up(v, dd);
            if (lane >= dd) v += y;
        }
        if (lane < nchunks) blocksums[lane] = v - x;
    }
    gbar(bar, bar + 1, nblk);

    // ---- P1c: add chunk offsets ----
    if ((int)blockIdx.x < nchunks) {
        int add = blocksums[blockIdx.x];
        int base = blockIdx.x * 1024 + t * 4;
        #pragma unroll
        for (int j = 0; j < 4; ++j)
            if (base + j < N) cursor[base + j] += add;
    }
    gbar(bar, bar + 1, nblk);

    // ---- P2: perm scatter ----
    for (int i = gid; i < E; i += G) {
        int d = edge_list[i].x;
        int p = atomicAdd(&cursor[d], 1);
        perm[p] = i;
    }
}

// ---------------- persistent fused MFMA MLP + segment scatter ----------------
// R8 version, byte-for-byte (194us, VGPR 84, 768 blocks, 3/CU).
// LDS map (48 KB):
//   [0,16K)  : B1 frags (W1 hi/lo)   -- persistent
//   [16,32K) : B2 frags (W2 hi/lo)   -- persistent
//   [32,48K) : h1 slices (4 KB/wave) aliased with ACC (64 seg x 64 f32)
// Per-tile: barriers (a) pre-LDS-atomics, (b) pre-flush, (c) post-flush,
// all lgkm-only. Tile T+1's seg scan overlaps tile T's GEMMs.

__global__ __launch_bounds__(256, 3) void edge_mlp_sorted(
    const float* __restrict__ atom,
    const float* __restrict__ edge_emb,
    const unsigned short* __restrict__ wpack,
    const float* __restrict__ b1,
    const float* __restrict__ b2,
    const float* __restrict__ coef,
    const int*   __restrict__ edge_list,       // [E,2]: [dest, src]
    const int*   __restrict__ perm,
    float* __restrict__ num,
    float* __restrict__ den,
    int E)
{
    __shared__ __align__(16) unsigned char SH[49152];
    __shared__ float denacc[TE];
    __shared__ int   segdest[TE];

    unsigned short* B1 = (unsigned short*)SH;            // W1 hi/lo frags
    unsigned short* B2 = (unsigned short*)(SH + 16384);  // W2 hi/lo frags
    float* H1  = (float*)(SH + 32768);                   // h1 slices / ACC
    float* ACC = H1;

    const int t    = threadIdx.x;
    const int w    = t >> 6;
    const int lane = t & 63;
    const int q    = lane >> 4;
    const int n    = lane & 15;
    const int ntiles = (E + TE - 1) / TE;
    const int stride = gridDim.x;

    // ---- one-time: W frags global->LDS, biases->regs, zero ACC/denacc ----
    {
        const uint4* wp = (const uint4*)wpack;
        uint4* shw = (uint4*)SH;
        #pragma unroll
        for (int i = 0; i < 8; ++i)
            shw[t + 256 * i] = wp[t + 256 * i];          // 32 KB
    }
    float b1v[4], b2v[4], cfv[4];
    #pragma unroll
    for (int nt = 0; nt < 4; ++nt) {
        b1v[nt] = b1[nt * 16 + n];
        b2v[nt] = b2[nt * 16 + n];
        cfv[nt] = coef[nt * 16 + n];
    }
    {
        float4 z4 = {0.f, 0.f, 0.f, 0.f};
        float4* az = (float4*)ACC;
        #pragma unroll
        for (int i = 0; i < 4; ++i) az[t + 256 * i] = z4;
        if (t < TE) denacc[t] = 0.f;
    }
    __syncthreads();

    // ---- prime: tile tt0 meta + rows; pA = perm ids of tile tt0+stride ----
    int tt = blockIdx.x;
    int m_head, m_sidx, m_d, m_nseg, m_seg[4], m_src[4];
    int pdnd = -1;
    int pA = 0;
    float4 rA0, rA1, rA2, rA3;
    {
        int eg = tt * TE + lane; if (eg >= E) eg = E - 1;
        int pc = perm[eg];
        int2 pr = ((const int2*)edge_list)[pc];
        int pid = __shfl(pc, w * 16 + n);
        const float* ep = edge_emb + (size_t)pid * HID;
        rA0 = *(const float4*)(ep + q * 8);
        rA1 = *(const float4*)(ep + q * 8 + 4);
        rA2 = *(const float4*)(ep + 32 + q * 8);
        rA3 = *(const float4*)(ep + 36 + q * 8);
        int eb = tt * TE;
        if (lane == 0 && eb > 0)       pdnd = edge_list[2 * perm[eb - 1]];
        if (lane == 63 && eb + TE < E) pdnd = edge_list[2 * perm[eb + TE]];
        tile_scan(pr, lane, w, q, m_head, m_sidx, m_d, m_nseg, m_seg, m_src);
        if (tt + stride < ntiles) {
            int eg2 = (tt + stride) * TE + lane; if (eg2 >= E) eg2 = E - 1;
            pA = perm[eg2];
        }
    }

    for (; tt < ntiles; tt += stride) {
        const int eb = tt * TE;
        const bool hn = (tt + stride) < ntiles;

        // ---- early atom gather (meta known at iter start) ----
        float av[4][4];
        #pragma unroll
        for (int r = 0; r < 4; ++r) {
            const float* ap = atom + (size_t)m_src[r] * HID + n;
            #pragma unroll
            for (int nt = 0; nt < 4; ++nt) av[r][nt] = ap[nt * 16];
        }

        // ---- prefetch tile T+1: pairs, rows, boundary; pB = ids(T+2) ----
        int2 pr_n = make_int2(0, 0);
        float4 rN0 = {0,0,0,0}, rN1 = {0,0,0,0}, rN2 = {0,0,0,0}, rN3 = {0,0,0,0};
        int pB = 0, pdnd_n = -1;
        if (hn) {
            pr_n = ((const int2*)edge_list)[pA];
            int pid2 = __shfl(pA, w * 16 + n);
            const float* ep2 = edge_emb + (size_t)pid2 * HID;
            rN0 = *(const float4*)(ep2 + q * 8);
            rN1 = *(const float4*)(ep2 + q * 8 + 4);
            rN2 = *(const float4*)(ep2 + 32 + q * 8);
            rN3 = *(const float4*)(ep2 + 36 + q * 8);
            int ebn = (tt + stride) * TE;
            if (lane == 0 && ebn > 0)       pdnd_n = edge_list[2 * perm[ebn - 1]];
            if (lane == 63 && ebn + TE < E) pdnd_n = edge_list[2 * perm[ebn + TE]];
            if (tt + 2 * stride < ntiles) {
                int eg3 = (tt + 2 * stride) * TE + lane; if (eg3 >= E) eg3 = E - 1;
                pB = perm[eg3];
            }
        }

        // ---- GEMM1: h1 = tanh(E @ W1 + b1), split-bf16 ----
        short8 a1h[2], a1l[2];
        split8(rA0, rA1, a1h[0], a1l[0]);
        split8(rA2, rA3, a1h[1], a1l[1]);
        float4v c1[4];
        #pragma unroll
        for (int i = 0; i < 4; ++i) c1[i] = (float4v){0.f, 0.f, 0.f, 0.f};
        #pragma unroll
        for (int nt = 0; nt < 4; ++nt) {
            #pragma unroll
            for (int ks = 0; ks < 2; ++ks) {
                int cb = (nt * 2 + ks) * 64 + lane;
                short8 bh = *(const short8*)&B1[cb * 8];
                short8 bl = *(const short8*)&B1[4096 + cb * 8];
                c1[nt] = __builtin_amdgcn_mfma_f32_16x16x32_bf16(a1h[ks], bh, c1[nt], 0, 0, 0);
                c1[nt] = __builtin_amdgcn_mfma_f32_16x16x32_bf16(a1h[ks], bl, c1[nt], 0, 0, 0);
                c1[nt] = __builtin_amdgcn_mfma_f32_16x16x32_bf16(a1l[ks], bh, c1[nt], 0, 0, 0);
            }
        }

        // ---- tile T+1 seg scan: DS latency overlaps the MFMA sections ----
        int nm_head = 0, nm_sidx = 0, nm_d = 0, nm_nseg = 0;
        int nm_seg[4] = {0,0,0,0}, nm_src[4] = {0,0,0,0};
        if (hn)
            tile_scan(pr_n, lane, w, q, nm_head, nm_sidx, nm_d, nm_nseg,
                      nm_seg, nm_src);

        // ---- tanh + h1 write (wave-local slice, swizzled) ----
        float* h1w = H1 + w * 1024;
        #pragma unroll
        for (int nt = 0; nt < 4; ++nt) {
            int f = nt * 16 + n;
            #pragma unroll
            for (int r = 0; r < 4; ++r) {
                int m = q * 4 + r;
                h1w[m * 64 + (f ^ ((m & 7) << 3))] = fast_tanh(c1[nt][r] + b1v[nt]);
            }
        }
        // wave-local fence (reads below are this wave's own slice)
        asm volatile("s_waitcnt lgkmcnt(0)" ::: "memory");
        __builtin_amdgcn_sched_barrier(0);

        // ---- read back as GEMM2 A frags, split to bf16 ----
        short8 a2h[2], a2l[2];
        {
            int m = n;
            #pragma unroll
            for (int ks2 = 0; ks2 < 2; ++ks2) {
                int F0 = (ks2 * 32 + q * 8) ^ ((m & 7) << 3);
                const float* sp = h1w + m * 64 + F0;
                float4 u0 = *(const float4*)&sp[0];
                float4 u1 = *(const float4*)&sp[4];
                split8(u0, u1, a2h[ks2], a2l[ks2]);
            }
        }
        // ---- zero own slice (becomes ACC rows w*16..w*16+15) ----
        {
            float4 z4 = {0.f, 0.f, 0.f, 0.f};
            float* zp = h1w + lane * 16;
            #pragma unroll
            for (int i = 0; i < 4; ++i) *(float4*)(zp + 4 * i) = z4;
        }

        // ---- GEMM2: h2 = h1 @ W2 + b2 ----
        float4v c2[4];
        #pragma unroll
        for (int i = 0; i < 4; ++i) c2[i] = (float4v){0.f, 0.f, 0.f, 0.f};
        #pragma unroll
        for (int nt = 0; nt < 4; ++nt) {
            #pragma unroll
            for (int ks = 0; ks < 2; ++ks) {
                int cb = (nt * 2 + ks) * 64 + lane;
                short8 bh = *(const short8*)&B2[cb * 8];
                short8 bl = *(const short8*)&B2[4096 + cb * 8];
                c2[nt] = __builtin_amdgcn_mfma_f32_16x16x32_bf16(a2h[ks], bh, c2[nt], 0, 0, 0);
                c2[nt] = __builtin_amdgcn_mfma_f32_16x16x32_bf16(a2h[ks], bl, c2[nt], 0, 0, 0);
                c2[nt] = __builtin_amdgcn_mfma_f32_16x16x32_bf16(a2l[ks], bh, c2[nt], 0, 0, 0);
            }
        }

        // ---- msg, attention ----
        float msg[4][4], partial[4], at[4];
        #pragma unroll
        for (int r = 0; r < 4; ++r) {
            float p = 0.f;
            #pragma unroll
            for (int nt = 0; nt < 4; ++nt) {
                float hv = c2[nt][r] + b2v[nt];
                msg[r][nt] = av[r][nt] * hv;
                p = fmaf(msg[r][nt], cfv[nt], p);
            }
            partial[r] = p;
        }
        #pragma unroll
        for (int m = 1; m < 16; m <<= 1) {
            #pragma unroll
            for (int r = 0; r < 4; ++r)
                partial[r] += __shfl_xor(partial[r], m);
        }
        #pragma unroll
        for (int r = 0; r < 4; ++r) {
            int eg = eb + w * 16 + q * 4 + r;
            at[r] = (eg < E) ? __expf(partial[r]) : 0.f;
        }

        bar_lgkm();        // (a) slice-zeros visible; prev flush reads done

        if (m_head) segdest[m_sidx] = m_d;

        // ---- register run-combine over 4 consecutive sorted edges ----
        {
            int curseg = m_seg[0];
            float acc0 = msg[0][0] * at[0], acc1 = msg[0][1] * at[0];
            float acc2 = msg[0][2] * at[0], acc3 = msg[0][3] * at[0];
            float rd = at[0];
            #pragma unroll
            for (int r = 1; r < 4; ++r) {
                if (m_seg[r] == curseg) {
                    acc0 = fmaf(msg[r][0], at[r], acc0);
                    acc1 = fmaf(msg[r][1], at[r], acc1);
                    acc2 = fmaf(msg[r][2], at[r], acc2);
                    acc3 = fmaf(msg[r][3], at[r], acc3);
                    rd += at[r];
                } else {
                    float* p = &ACC[curseg * 64 + n];
                    atomicAdd(p + 0,  acc0); atomicAdd(p + 16, acc1);
                    atomicAdd(p + 32, acc2); atomicAdd(p + 48, acc3);
                    if (n == 0) atomicAdd(&denacc[curseg], rd);
                    curseg = m_seg[r];
                    acc0 = msg[r][0] * at[r]; acc1 = msg[r][1] * at[r];
                    acc2 = msg[r][2] * at[r]; acc3 = msg[r][3] * at[r];
                    rd = at[r];
                }
            }
            float* p = &ACC[curseg * 64 + n];
            atomicAdd(p + 0,  acc0); atomicAdd(p + 16, acc1);
            atomicAdd(p + 32, acc2); atomicAdd(p + 48, acc3);
            if (n == 0) atomicAdd(&denacc[curseg], rd);
        }

        bar_lgkm();        // (b) LDS atomics done

        // ---- flush: interior = stores, boundary = atomics ----
        {
            int prevd = __shfl(pdnd, 0);
            int nextd = __shfl(pdnd, 63);
            int sg = t >> 2;
            int qq = t & 3;
            if (sg < m_nseg) {
                int d2 = segdest[sg];
                bool bnd = (sg == 0 && d2 == prevd) ||
                           (sg == m_nseg - 1 && d2 == nextd);
                float* np = num + (size_t)d2 * HID + qq * 16;
                const float* sp = &ACC[sg * 64 + qq * 16];
                if (bnd) {
                    #pragma unroll
                    for (int j = 0; j < 16; ++j) atomicAdd(np + j, sp[j]);
                    if (qq == 0) { atomicAdd(&den[d2], denacc[sg]); denacc[sg] = 0.f; }
                } else {
                    #pragma unroll
                    for (int j = 0; j < 4; ++j)
                        ((float4*)np)[j] = *(const float4*)(sp + 4 * j);
                    if (qq == 0) { den[d2] = denacc[sg]; denacc[sg] = 0.f; }
                }
            }
        }

        bar_lgkm();        // (c) flush LDS reads done before next h1 write

        if (hn) {
            m_head = nm_head; m_sidx = nm_sidx; m_d = nm_d; m_nseg = nm_nseg;
            #pragma unroll
            for (int r = 0; r < 4; ++r) { m_seg[r] = nm_seg[r]; m_src[r] = nm_src[r]; }
            pdnd = pdnd_n;
            rA0 = rN0; rA1 = rN1; rA2 = rN2; rA3 = rN3;
            pA = pB;
        }
    }
}

__global__ __launch_bounds__(256) void finalize_kernel(
    float* __restrict__ out, const float* __restrict__ den, int n16)
{
    int i = blockIdx.x * blockDim.x + threadIdx.x;
    if (i >= n16) return;
    float d = den[i >> 4];
    if (d > 0.f) {
        float4* p = (float4*)out + i;
        float4 v = *p;
        float r = 1.0f / d;
        v.x *= r; v.y *= r; v.z *= r; v.w *= r;
        *p = v;
    }
}

extern "C" void kernel_launch(void* const* d_in, const int* in_sizes, int n_in,
                              void* d_out, int out_size, void* d_ws, size_t ws_size,
                              hipStream_t stream) {
    const float* atom      = (const float*)d_in[0];
    const float* edge_emb  = (const float*)d_in[1];
    const float* W1        = (const float*)d_in[2];
    const float* b1        = (const float*)d_in[3];
    const float* W2        = (const float*)d_in[4];
    const float* b2        = (const float*)d_in[5];
    const float* coef      = (const float*)d_in[6];
    const int*   edge_list = (const int*)d_in[7];

    const int N = in_sizes[0] / HID;   // 50000
    const int E = in_sizes[1] / HID;   // 800000

    // ws: [den N f32][cursor N i32][blocksums 64][bar 64][perm E i32]
    //     [wpack 16384 u16]
    float* den       = (float*)d_ws;
    int*   cursor    = (int*)d_ws + N;
    int*   blocksums = (int*)d_ws + 2 * N;
    int*   bar       = (int*)d_ws + 2 * N + 64;
    int*   perm      = (int*)d_ws + 2 * N + 128;
    unsigned short* wpack = (unsigned short*)((int*)d_ws + 2 * N + 128 + E);

    // zero den + cursor + blocksums + barrier state
    hipMemsetAsync(d_ws, 0, (size_t)(2 * N + 128) * sizeof(int), stream);

    int n4 = N * (HID / 4);                       // float4 count of out
    aux_mega<<<NBLK_AUX, 256, 0, stream>>>(
        (const int2*)edge_list, cursor, blocksums, bar, perm, E, N,
        W1, W2, wpack, (float4*)d_out, n4);

    int ntl  = (E + TE - 1) / TE;
    int nblk = ntl < NBLK_MLP ? ntl : NBLK_MLP;
    edge_mlp_sorted<<<nblk, 256, 0, stream>>>(
        atom, edge_emb, wpack, b1, b2, coef, edge_list, perm,
        (float*)d_out, den, E);

    finalize_kernel<<<(n4 + 255) / 256, 256, 0, stream>>>((float*)d_out, den, n4);
}

// Round 6
// 470.838 us; speedup vs baseline: 1.6598x; 1.6598x over previous
//
#include <hip/hip_runtime.h>
#include <math.h>

// ContinuousFilterConv, round 11: recombine proven parts; no grid barriers.
// R10 post-mortem: device-scope grid barrier = 385us of spin (each block
// arrival forces an L2 wb/inv on non-coherent per-XCD L2s). Mega-kernel
// abandoned; stream-ordered dispatches are strictly cheaper here.
// R11 = R8's edge_mlp (byte-identical, proven 194us) +
//       R8's hist_pack fusion (hist + W-pack + out-zero) +
//       R7's parallel 3-kernel scan (scan_single cost ~14us) +
//       NEW rank trick: hist_pack stores rank[i] = atomicAdd(cursor[d],1)
//       (u16); perm becomes p = cursor[d] + rank[i] -- the 800K global
//       atomic RMW pass in perm_kernel is eliminated.
// Numerics identical (passed, absmax 0.03125).

#define TE 64
#define HID 64
#define NBLK_MLP 768

typedef __attribute__((ext_vector_type(8))) short short8;
typedef __attribute__((ext_vector_type(4))) float float4v;

__device__ __forceinline__ float fast_tanh(float x) {
    float t = __expf(2.0f * x);
    return 1.0f - 2.0f * __builtin_amdgcn_rcpf(t + 1.0f);
}

__device__ __forceinline__ void split_bf16(float x, unsigned short& hi,
                                           unsigned short& lo) {
    unsigned b = __float_as_uint(x);
    hi = (unsigned short)(b >> 16);
    float hf = __uint_as_float(b & 0xffff0000u);
    lo = (unsigned short)(__float_as_uint(x - hf) >> 16);
}

__device__ __forceinline__ void split8(const float4 u0, const float4 u1,
                                       short8& h, short8& l) {
    float xv[8] = {u0.x, u0.y, u0.z, u0.w, u1.x, u1.y, u1.z, u1.w};
    #pragma unroll
    for (int j = 0; j < 8; ++j) {
        unsigned short hi, lo;
        split_bf16(xv[j], hi, lo);
        h[j] = (short)hi; l[j] = (short)lo;
    }
}

// lgkm-only barrier: LDS ordering without draining global loads/stores.
__device__ __forceinline__ void bar_lgkm() {
    asm volatile("s_waitcnt lgkmcnt(0)" ::: "memory");
    __builtin_amdgcn_sched_barrier(0);
    __builtin_amdgcn_s_barrier();
    __builtin_amdgcn_sched_barrier(0);
}

// Segmentation scan for one 64-edge tile (wave-redundant, lane <-> edge).
__device__ __forceinline__ void tile_scan(int2 pr, int lane, int w, int q,
    int& M_head, int& M_sidx, int& M_d, int& M_nseg,
    int* M_seg, int* M_src)
{
    int d = pr.x, s = pr.y;
    int dprev = __shfl_up(d, 1);
    M_head = (lane == 0 || dprev != d) ? 1 : 0;
    int sv = M_head;
    #pragma unroll
    for (int m = 1; m < 64; m <<= 1) {
        int y = __shfl_up(sv, m);
        if (lane >= m) sv += y;
    }
    M_sidx = sv - 1;
    M_d = d;
    M_nseg = __shfl(sv, 63);
    #pragma unroll
    for (int r = 0; r < 4; ++r) {
        int el = w * 16 + q * 4 + r;
        M_seg[r] = __shfl(M_sidx, el);
        M_src[r] = __shfl(s, el);
    }
}

// ---------------- fused hist + rank + W-pack + out-zero ----------------
// B frag for 16x16x32: lane(q,n) holds B[k=ks*32+q*8+j][f=nt*16+n], j=0..7.
// Linear: chunk = (nt*2+ks)*64 + q*16 + n, elem = chunk*8 + j.
// wpack: [W1h 4096][W1l 4096][W2h 4096][W2l 4096] u16.
__global__ __launch_bounds__(256) void hist_pack(
    const int2* __restrict__ edge_list, int* __restrict__ cursor,
    unsigned short* __restrict__ rank, int E,
    const float* __restrict__ W1, const float* __restrict__ W2,
    unsigned short* __restrict__ wpack,
    float4* __restrict__ out4, int n4)
{
    int i = blockIdx.x * 256 + threadIdx.x;
    if (i < E) {
        int r = atomicAdd(&cursor[edge_list[i].x], 1);
        rank[i] = (unsigned short)r;
    }
    if (i < n4) out4[i] = (float4){0.f, 0.f, 0.f, 0.f};
    if (i < 4096) {
        int idx = i;
        int k = idx >> 6, f = idx & 63;
        int nt = f >> 4, n = f & 15, ks = k >> 5, q = (k >> 3) & 3, j = k & 7;
        int fi = (((nt * 2 + ks) * 4 + q) * 16 + n) * 8 + j;
        unsigned short hi, lo;
        split_bf16(W1[idx], hi, lo);
        wpack[fi] = hi; wpack[4096 + fi] = lo;
        split_bf16(W2[idx], hi, lo);
        wpack[8192 + fi] = hi; wpack[12288 + fi] = lo;
    }
}

// ---------------- parallel 3-kernel scan (known-good from R7) ----------------
__global__ __launch_bounds__(1024) void scanA_kernel(
    int* __restrict__ a, int* __restrict__ blocksums, int N)
{
    __shared__ int wsum[16];
    const int t = threadIdx.x;
    const int lane = t & 63, wv = t >> 6;
    int i = blockIdx.x * 1024 + t;
    int x = (i < N) ? a[i] : 0;
    int v = x;
    #pragma unroll
    for (int d = 1; d < 64; d <<= 1) {
        int y = __shfl_up(v, d);
        if (lane >= d) v += y;
    }
    if (lane == 63) wsum[wv] = v;
    __syncthreads();
    if (wv == 0 && lane < 16) {
        int s = wsum[lane];
        #pragma unroll
        for (int d = 1; d < 16; d <<= 1) {
            int y = __shfl_up(s, d);
            if (lane >= d) s += y;
        }
        wsum[lane] = s;
    }
    __syncthreads();
    int incl = v + ((wv == 0) ? 0 : wsum[wv - 1]);
    if (i < N) a[i] = incl - x;
    if (t == 1023) blocksums[blockIdx.x] = incl;
}

__global__ __launch_bounds__(64) void scanB_kernel(int* __restrict__ bs, int nb)
{
    int lane = threadIdx.x;
    int x = (lane < nb) ? bs[lane] : 0;
    int v = x;
    #pragma unroll
    for (int d = 1; d < 64; d <<= 1) {
        int y = __shfl_up(v, d);
        if (lane >= d) v += y;
    }
    if (lane < nb) bs[lane] = v - x;
}

__global__ __launch_bounds__(1024) void scanC_kernel(
    int* __restrict__ a, const int* __restrict__ blocksums, int N)
{
    int i = blockIdx.x * 1024 + threadIdx.x;
    if (i < N) a[i] += blocksums[blockIdx.x];
}

// perm scatter WITHOUT atomics: p = start[d] + rank[i].
__global__ __launch_bounds__(256) void perm_kernel(
    const int2* __restrict__ edge_list, const int* __restrict__ cursor,
    const unsigned short* __restrict__ rank, int* __restrict__ perm, int E)
{
    int i = blockIdx.x * blockDim.x + threadIdx.x;
    if (i < E) {
        int d = edge_list[i].x;
        int p = cursor[d] + (int)rank[i];
        perm[p] = i;
    }
}

// ---------------- persistent fused MFMA MLP + segment scatter ----------------
// R8 version, byte-for-byte (194us, VGPR 84, 768 blocks, 3/CU).
// LDS map (48 KB):
//   [0,16K)  : B1 frags (W1 hi/lo)   -- persistent
//   [16,32K) : B2 frags (W2 hi/lo)   -- persistent
//   [32,48K) : h1 slices (4 KB/wave) aliased with ACC (64 seg x 64 f32)
// Per-tile: barriers (a) pre-LDS-atomics, (b) pre-flush, (c) post-flush,
// all lgkm-only. Tile T+1's seg scan overlaps tile T's GEMMs.

__global__ __launch_bounds__(256, 3) void edge_mlp_sorted(
    const float* __restrict__ atom,
    const float* __restrict__ edge_emb,
    const unsigned short* __restrict__ wpack,
    const float* __restrict__ b1,
    const float* __restrict__ b2,
    const float* __restrict__ coef,
    const int*   __restrict__ edge_list,       // [E,2]: [dest, src]
    const int*   __restrict__ perm,
    float* __restrict__ num,
    float* __restrict__ den,
    int E)
{
    __shared__ __align__(16) unsigned char SH[49152];
    __shared__ float denacc[TE];
    __shared__ int   segdest[TE];

    unsigned short* B1 = (unsigned short*)SH;            // W1 hi/lo frags
    unsigned short* B2 = (unsigned short*)(SH + 16384);  // W2 hi/lo frags
    float* H1  = (float*)(SH + 32768);                   // h1 slices / ACC
    float* ACC = H1;

    const int t    = threadIdx.x;
    const int w    = t >> 6;
    const int lane = t & 63;
    const int q    = lane >> 4;
    const int n    = lane & 15;
    const int ntiles = (E + TE - 1) / TE;
    const int stride = gridDim.x;

    // ---- one-time: W frags global->LDS, biases->regs, zero ACC/denacc ----
    {
        const uint4* wp = (const uint4*)wpack;
        uint4* shw = (uint4*)SH;
        #pragma unroll
        for (int i = 0; i < 8; ++i)
            shw[t + 256 * i] = wp[t + 256 * i];          // 32 KB
    }
    float b1v[4], b2v[4], cfv[4];
    #pragma unroll
    for (int nt = 0; nt < 4; ++nt) {
        b1v[nt] = b1[nt * 16 + n];
        b2v[nt] = b2[nt * 16 + n];
        cfv[nt] = coef[nt * 16 + n];
    }
    {
        float4 z4 = {0.f, 0.f, 0.f, 0.f};
        float4* az = (float4*)ACC;
        #pragma unroll
        for (int i = 0; i < 4; ++i) az[t + 256 * i] = z4;
        if (t < TE) denacc[t] = 0.f;
    }
    __syncthreads();

    // ---- prime: tile tt0 meta + rows; pA = perm ids of tile tt0+stride ----
    int tt = blockIdx.x;
    int m_head, m_sidx, m_d, m_nseg, m_seg[4], m_src[4];
    int pdnd = -1;
    int pA = 0;
    float4 rA0, rA1, rA2, rA3;
    {
        int eg = tt * TE + lane; if (eg >= E) eg = E - 1;
        int pc = perm[eg];
        int2 pr = ((const int2*)edge_list)[pc];
        int pid = __shfl(pc, w * 16 + n);
        const float* ep = edge_emb + (size_t)pid * HID;
        rA0 = *(const float4*)(ep + q * 8);
        rA1 = *(const float4*)(ep + q * 8 + 4);
        rA2 = *(const float4*)(ep + 32 + q * 8);
        rA3 = *(const float4*)(ep + 36 + q * 8);
        int eb = tt * TE;
        if (lane == 0 && eb > 0)       pdnd = edge_list[2 * perm[eb - 1]];
        if (lane == 63 && eb + TE < E) pdnd = edge_list[2 * perm[eb + TE]];
        tile_scan(pr, lane, w, q, m_head, m_sidx, m_d, m_nseg, m_seg, m_src);
        if (tt + stride < ntiles) {
            int eg2 = (tt + stride) * TE + lane; if (eg2 >= E) eg2 = E - 1;
            pA = perm[eg2];
        }
    }

    for (; tt < ntiles; tt += stride) {
        const int eb = tt * TE;
        const bool hn = (tt + stride) < ntiles;

        // ---- early atom gather (meta known at iter start) ----
        float av[4][4];
        #pragma unroll
        for (int r = 0; r < 4; ++r) {
            const float* ap = atom + (size_t)m_src[r] * HID + n;
            #pragma unroll
            for (int nt = 0; nt < 4; ++nt) av[r][nt] = ap[nt * 16];
        }

        // ---- prefetch tile T+1: pairs, rows, boundary; pB = ids(T+2) ----
        int2 pr_n = make_int2(0, 0);
        float4 rN0 = {0,0,0,0}, rN1 = {0,0,0,0}, rN2 = {0,0,0,0}, rN3 = {0,0,0,0};
        int pB = 0, pdnd_n = -1;
        if (hn) {
            pr_n = ((const int2*)edge_list)[pA];
            int pid2 = __shfl(pA, w * 16 + n);
            const float* ep2 = edge_emb + (size_t)pid2 * HID;
            rN0 = *(const float4*)(ep2 + q * 8);
            rN1 = *(const float4*)(ep2 + q * 8 + 4);
            rN2 = *(const float4*)(ep2 + 32 + q * 8);
            rN3 = *(const float4*)(ep2 + 36 + q * 8);
            int ebn = (tt + stride) * TE;
            if (lane == 0 && ebn > 0)       pdnd_n = edge_list[2 * perm[ebn - 1]];
            if (lane == 63 && ebn + TE < E) pdnd_n = edge_list[2 * perm[ebn + TE]];
            if (tt + 2 * stride < ntiles) {
                int eg3 = (tt + 2 * stride) * TE + lane; if (eg3 >= E) eg3 = E - 1;
                pB = perm[eg3];
            }
        }

        // ---- GEMM1: h1 = tanh(E @ W1 + b1), split-bf16 ----
        short8 a1h[2], a1l[2];
        split8(rA0, rA1, a1h[0], a1l[0]);
        split8(rA2, rA3, a1h[1], a1l[1]);
        float4v c1[4];
        #pragma unroll
        for (int i = 0; i < 4; ++i) c1[i] = (float4v){0.f, 0.f, 0.f, 0.f};
        #pragma unroll
        for (int nt = 0; nt < 4; ++nt) {
            #pragma unroll
            for (int ks = 0; ks < 2; ++ks) {
                int cb = (nt * 2 + ks) * 64 + lane;
                short8 bh = *(const short8*)&B1[cb * 8];
                short8 bl = *(const short8*)&B1[4096 + cb * 8];
                c1[nt] = __builtin_amdgcn_mfma_f32_16x16x32_bf16(a1h[ks], bh, c1[nt], 0, 0, 0);
                c1[nt] = __builtin_amdgcn_mfma_f32_16x16x32_bf16(a1h[ks], bl, c1[nt], 0, 0, 0);
                c1[nt] = __builtin_amdgcn_mfma_f32_16x16x32_bf16(a1l[ks], bh, c1[nt], 0, 0, 0);
            }
        }

        // ---- tile T+1 seg scan: DS latency overlaps the MFMA sections ----
        int nm_head = 0, nm_sidx = 0, nm_d = 0, nm_nseg = 0;
        int nm_seg[4] = {0,0,0,0}, nm_src[4] = {0,0,0,0};
        if (hn)
            tile_scan(pr_n, lane, w, q, nm_head, nm_sidx, nm_d, nm_nseg,
                      nm_seg, nm_src);

        // ---- tanh + h1 write (wave-local slice, swizzled) ----
        float* h1w = H1 + w * 1024;
        #pragma unroll
        for (int nt = 0; nt < 4; ++nt) {
            int f = nt * 16 + n;
            #pragma unroll
            for (int r = 0; r < 4; ++r) {
                int m = q * 4 + r;
                h1w[m * 64 + (f ^ ((m & 7) << 3))] = fast_tanh(c1[nt][r] + b1v[nt]);
            }
        }
        // wave-local fence (reads below are this wave's own slice)
        asm volatile("s_waitcnt lgkmcnt(0)" ::: "memory");
        __builtin_amdgcn_sched_barrier(0);

        // ---- read back as GEMM2 A frags, split to bf16 ----
        short8 a2h[2], a2l[2];
        {
            int m = n;
            #pragma unroll
            for (int ks2 = 0; ks2 < 2; ++ks2) {
                int F0 = (ks2 * 32 + q * 8) ^ ((m & 7) << 3);
                const float* sp = h1w + m * 64 + F0;
                float4 u0 = *(const float4*)&sp[0];
                float4 u1 = *(const float4*)&sp[4];
                split8(u0, u1, a2h[ks2], a2l[ks2]);
            }
        }
        // ---- zero own slice (becomes ACC rows w*16..w*16+15) ----
        {
            float4 z4 = {0.f, 0.f, 0.f, 0.f};
            float* zp = h1w + lane * 16;
            #pragma unroll
            for (int i = 0; i < 4; ++i) *(float4*)(zp + 4 * i) = z4;
        }

        // ---- GEMM2: h2 = h1 @ W2 + b2 ----
        float4v c2[4];
        #pragma unroll
        for (int i = 0; i < 4; ++i) c2[i] = (float4v){0.f, 0.f, 0.f, 0.f};
        #pragma unroll
        for (int nt = 0; nt < 4; ++nt) {
            #pragma unroll
            for (int ks = 0; ks < 2; ++ks) {
                int cb = (nt * 2 + ks) * 64 + lane;
                short8 bh = *(const short8*)&B2[cb * 8];
                short8 bl = *(const short8*)&B2[4096 + cb * 8];
                c2[nt] = __builtin_amdgcn_mfma_f32_16x16x32_bf16(a2h[ks], bh, c2[nt], 0, 0, 0);
                c2[nt] = __builtin_amdgcn_mfma_f32_16x16x32_bf16(a2h[ks], bl, c2[nt], 0, 0, 0);
                c2[nt] = __builtin_amdgcn_mfma_f32_16x16x32_bf16(a2l[ks], bh, c2[nt], 0, 0, 0);
            }
        }

        // ---- msg, attention ----
        float msg[4][4], partial[4], at[4];
        #pragma unroll
        for (int r = 0; r < 4; ++r) {
            float p = 0.f;
            #pragma unroll
            for (int nt = 0; nt < 4; ++nt) {
                float hv = c2[nt][r] + b2v[nt];
                msg[r][nt] = av[r][nt] * hv;
                p = fmaf(msg[r][nt], cfv[nt], p);
            }
            partial[r] = p;
        }
        #pragma unroll
        for (int m = 1; m < 16; m <<= 1) {
            #pragma unroll
            for (int r = 0; r < 4; ++r)
                partial[r] += __shfl_xor(partial[r], m);
        }
        #pragma unroll
        for (int r = 0; r < 4; ++r) {
            int eg = eb + w * 16 + q * 4 + r;
            at[r] = (eg < E) ? __expf(partial[r]) : 0.f;
        }

        bar_lgkm();        // (a) slice-zeros visible; prev flush reads done

        if (m_head) segdest[m_sidx] = m_d;

        // ---- register run-combine over 4 consecutive sorted edges ----
        {
            int curseg = m_seg[0];
            float acc0 = msg[0][0] * at[0], acc1 = msg[0][1] * at[0];
            float acc2 = msg[0][2] * at[0], acc3 = msg[0][3] * at[0];
            float rd = at[0];
            #pragma unroll
            for (int r = 1; r < 4; ++r) {
                if (m_seg[r] == curseg) {
                    acc0 = fmaf(msg[r][0], at[r], acc0);
                    acc1 = fmaf(msg[r][1], at[r], acc1);
                    acc2 = fmaf(msg[r][2], at[r], acc2);
                    acc3 = fmaf(msg[r][3], at[r], acc3);
                    rd += at[r];
                } else {
                    float* p = &ACC[curseg * 64 + n];
                    atomicAdd(p + 0,  acc0); atomicAdd(p + 16, acc1);
                    atomicAdd(p + 32, acc2); atomicAdd(p + 48, acc3);
                    if (n == 0) atomicAdd(&denacc[curseg], rd);
                    curseg = m_seg[r];
                    acc0 = msg[r][0] * at[r]; acc1 = msg[r][1] * at[r];
                    acc2 = msg[r][2] * at[r]; acc3 = msg[r][3] * at[r];
                    rd = at[r];
                }
            }
            float* p = &ACC[curseg * 64 + n];
            atomicAdd(p + 0,  acc0); atomicAdd(p + 16, acc1);
            atomicAdd(p + 32, acc2); atomicAdd(p + 48, acc3);
            if (n == 0) atomicAdd(&denacc[curseg], rd);
        }

        bar_lgkm();        // (b) LDS atomics done

        // ---- flush: interior = stores, boundary = atomics ----
        {
            int prevd = __shfl(pdnd, 0);
            int nextd = __shfl(pdnd, 63);
            int sg = t >> 2;
            int qq = t & 3;
            if (sg < m_nseg) {
                int d2 = segdest[sg];
                bool bnd = (sg == 0 && d2 == prevd) ||
                           (sg == m_nseg - 1 && d2 == nextd);
                float* np = num + (size_t)d2 * HID + qq * 16;
                const float* sp = &ACC[sg * 64 + qq * 16];
                if (bnd) {
                    #pragma unroll
                    for (int j = 0; j < 16; ++j) atomicAdd(np + j, sp[j]);
                    if (qq == 0) { atomicAdd(&den[d2], denacc[sg]); denacc[sg] = 0.f; }
                } else {
                    #pragma unroll
                    for (int j = 0; j < 4; ++j)
                        ((float4*)np)[j] = *(const float4*)(sp + 4 * j);
                    if (qq == 0) { den[d2] = denacc[sg]; denacc[sg] = 0.f; }
                }
            }
        }

        bar_lgkm();        // (c) flush LDS reads done before next h1 write

        if (hn) {
            m_head = nm_head; m_sidx = nm_sidx; m_d = nm_d; m_nseg = nm_nseg;
            #pragma unroll
            for (int r = 0; r < 4; ++r) { m_seg[r] = nm_seg[r]; m_src[r] = nm_src[r]; }
            pdnd = pdnd_n;
            rA0 = rN0; rA1 = rN1; rA2 = rN2; rA3 = rN3;
            pA = pB;
        }
    }
}

__global__ __launch_bounds__(256) void finalize_kernel(
    float* __restrict__ out, const float* __restrict__ den, int n16)
{
    int i = blockIdx.x * blockDim.x + threadIdx.x;
    if (i >= n16) return;
    float d = den[i >> 4];
    if (d > 0.f) {
        float4* p = (float4*)out + i;
        float4 v = *p;
        float r = 1.0f / d;
        v.x *= r; v.y *= r; v.z *= r; v.w *= r;
        *p = v;
    }
}

extern "C" void kernel_launch(void* const* d_in, const int* in_sizes, int n_in,
                              void* d_out, int out_size, void* d_ws, size_t ws_size,
                              hipStream_t stream) {
    const float* atom      = (const float*)d_in[0];
    const float* edge_emb  = (const float*)d_in[1];
    const float* W1        = (const float*)d_in[2];
    const float* b1        = (const float*)d_in[3];
    const float* W2        = (const float*)d_in[4];
    const float* b2        = (const float*)d_in[5];
    const float* coef      = (const float*)d_in[6];
    const int*   edge_list = (const int*)d_in[7];

    const int N = in_sizes[0] / HID;   // 50000
    const int E = in_sizes[1] / HID;   // 800000

    // ws: [den N f32][cursor N i32][blocksums 64][perm E i32]
    //     [rank E u16 -> E/2 ints][wpack 16384 u16]
    float* den       = (float*)d_ws;
    int*   cursor    = (int*)d_ws + N;
    int*   blocksums = (int*)d_ws + 2 * N;
    int*   perm      = (int*)d_ws + 2 * N + 64;
    unsigned short* rank  = (unsigned short*)((int*)d_ws + 2 * N + 64 + E);
    unsigned short* wpack = rank + E;

    // zero den + cursor (+blocksums region is overwritten by scanA)
    hipMemsetAsync(d_ws, 0, (size_t)(2 * N) * sizeof(int), stream);

    int n4   = N * (HID / 4);                     // float4 count of out
    int eblk = (E + 255) / 256;
    int nb   = (N + 1023) / 1024;
    int ghp  = eblk > (n4 + 255) / 256 ? eblk : (n4 + 255) / 256;
    hist_pack<<<ghp, 256, 0, stream>>>((const int2*)edge_list, cursor, rank, E,
                                       W1, W2, wpack, (float4*)d_out, n4);
    scanA_kernel<<<nb, 1024, 0, stream>>>(cursor, blocksums, N);
    scanB_kernel<<<1, 64, 0, stream>>>(blocksums, nb);
    scanC_kernel<<<nb, 1024, 0, stream>>>(cursor, blocksums, N);
    perm_kernel<<<eblk, 256, 0, stream>>>((const int2*)edge_list, cursor, rank,
                                          perm, E);

    int ntl  = (E + TE - 1) / TE;
    int nblk = ntl < NBLK_MLP ? ntl : NBLK_MLP;
    edge_mlp_sorted<<<nblk, 256, 0, stream>>>(
        atom, edge_emb, wpack, b1, b2, coef, edge_list, perm,
        (float*)d_out, den, E);

    finalize_kernel<<<(n4 + 255) / 256, 256, 0, stream>>>((float*)d_out, den, n4);
}

// Round 7
// 466.094 us; speedup vs baseline: 1.6767x; 1.0102x over previous
//
#include <hip/hip_runtime.h>
#include <math.h>

// ContinuousFilterConv, round 12: dispatch-gap test. R11 analysis: aux
// kernels sum to ~70us of GPU work but the non-MLP residual is ~276us ->
// ~200us is inter-dispatch bubbles (~25us/boundary, invariant across aux
// rewrites). R12 folds scanB+scanC into perm (each perm block redundantly
// wave-scans the 49 chunk sums in LDS: p = cursor[d]+bscan[d>>10]+rank[i]).
// Dispatches 8 -> 6. edge_mlp_sorted BYTE-IDENTICAL to R11 (195us proven)
// so the total delta cleanly attributes to the removed boundaries.
// Numerics identical (passed, absmax 0.03125).

#define TE 64
#define HID 64
#define NBLK_MLP 768

typedef __attribute__((ext_vector_type(8))) short short8;
typedef __attribute__((ext_vector_type(4))) float float4v;

__device__ __forceinline__ float fast_tanh(float x) {
    float t = __expf(2.0f * x);
    return 1.0f - 2.0f * __builtin_amdgcn_rcpf(t + 1.0f);
}

__device__ __forceinline__ void split_bf16(float x, unsigned short& hi,
                                           unsigned short& lo) {
    unsigned b = __float_as_uint(x);
    hi = (unsigned short)(b >> 16);
    float hf = __uint_as_float(b & 0xffff0000u);
    lo = (unsigned short)(__float_as_uint(x - hf) >> 16);
}

__device__ __forceinline__ void split8(const float4 u0, const float4 u1,
                                       short8& h, short8& l) {
    float xv[8] = {u0.x, u0.y, u0.z, u0.w, u1.x, u1.y, u1.z, u1.w};
    #pragma unroll
    for (int j = 0; j < 8; ++j) {
        unsigned short hi, lo;
        split_bf16(xv[j], hi, lo);
        h[j] = (short)hi; l[j] = (short)lo;
    }
}

// lgkm-only barrier: LDS ordering without draining global loads/stores.
__device__ __forceinline__ void bar_lgkm() {
    asm volatile("s_waitcnt lgkmcnt(0)" ::: "memory");
    __builtin_amdgcn_sched_barrier(0);
    __builtin_amdgcn_s_barrier();
    __builtin_amdgcn_sched_barrier(0);
}

// Segmentation scan for one 64-edge tile (wave-redundant, lane <-> edge).
__device__ __forceinline__ void tile_scan(int2 pr, int lane, int w, int q,
    int& M_head, int& M_sidx, int& M_d, int& M_nseg,
    int* M_seg, int* M_src)
{
    int d = pr.x, s = pr.y;
    int dprev = __shfl_up(d, 1);
    M_head = (lane == 0 || dprev != d) ? 1 : 0;
    int sv = M_head;
    #pragma unroll
    for (int m = 1; m < 64; m <<= 1) {
        int y = __shfl_up(sv, m);
        if (lane >= m) sv += y;
    }
    M_sidx = sv - 1;
    M_d = d;
    M_nseg = __shfl(sv, 63);
    #pragma unroll
    for (int r = 0; r < 4; ++r) {
        int el = w * 16 + q * 4 + r;
        M_seg[r] = __shfl(M_sidx, el);
        M_src[r] = __shfl(s, el);
    }
}

// ---------------- fused hist + rank + W-pack + out-zero ----------------
// B frag for 16x16x32: lane(q,n) holds B[k=ks*32+q*8+j][f=nt*16+n], j=0..7.
// Linear: chunk = (nt*2+ks)*64 + q*16 + n, elem = chunk*8 + j.
// wpack: [W1h 4096][W1l 4096][W2h 4096][W2l 4096] u16.
__global__ __launch_bounds__(256) void hist_pack(
    const int2* __restrict__ edge_list, int* __restrict__ cursor,
    unsigned short* __restrict__ rank, int E,
    const float* __restrict__ W1, const float* __restrict__ W2,
    unsigned short* __restrict__ wpack,
    float4* __restrict__ out4, int n4)
{
    int i = blockIdx.x * 256 + threadIdx.x;
    if (i < E) {
        int r = atomicAdd(&cursor[edge_list[i].x], 1);
        rank[i] = (unsigned short)r;
    }
    if (i < n4) out4[i] = (float4){0.f, 0.f, 0.f, 0.f};
    if (i < 4096) {
        int idx = i;
        int k = idx >> 6, f = idx & 63;
        int nt = f >> 4, n = f & 15, ks = k >> 5, q = (k >> 3) & 3, j = k & 7;
        int fi = (((nt * 2 + ks) * 4 + q) * 16 + n) * 8 + j;
        unsigned short hi, lo;
        split_bf16(W1[idx], hi, lo);
        wpack[fi] = hi; wpack[4096 + fi] = lo;
        split_bf16(W2[idx], hi, lo);
        wpack[8192 + fi] = hi; wpack[12288 + fi] = lo;
    }
}

// ---------------- scanA: per-1024-chunk local exclusive scan ----------------
__global__ __launch_bounds__(1024) void scanA_kernel(
    int* __restrict__ a, int* __restrict__ blocksums, int N)
{
    __shared__ int wsum[16];
    const int t = threadIdx.x;
    const int lane = t & 63, wv = t >> 6;
    int i = blockIdx.x * 1024 + t;
    int x = (i < N) ? a[i] : 0;
    int v = x;
    #pragma unroll
    for (int d = 1; d < 64; d <<= 1) {
        int y = __shfl_up(v, d);
        if (lane >= d) v += y;
    }
    if (lane == 63) wsum[wv] = v;
    __syncthreads();
    if (wv == 0 && lane < 16) {
        int s = wsum[lane];
        #pragma unroll
        for (int d = 1; d < 16; d <<= 1) {
            int y = __shfl_up(s, d);
            if (lane >= d) s += y;
        }
        wsum[lane] = s;
    }
    __syncthreads();
    int incl = v + ((wv == 0) ? 0 : wsum[wv - 1]);
    if (i < N) a[i] = incl - x;
    if (t == 1023) blocksums[blockIdx.x] = incl;
}

// ---------------- perm2: fused chunk-sum scan + scatter (no atomics) --------
// Each block redundantly wave-scans the nb (<=64) chunk sums, then
// p = cursor[d] + bscan[d>>10] + rank[i].
__global__ __launch_bounds__(256) void perm2_kernel(
    const int2* __restrict__ edge_list, const int* __restrict__ cursor,
    const int* __restrict__ blocksums, int nb,
    const unsigned short* __restrict__ rank, int* __restrict__ perm, int E)
{
    __shared__ int bscan[64];
    const int t = threadIdx.x;
    if (t < 64) {                      // wave 0 exactly
        int x = (t < nb) ? blocksums[t] : 0;
        int v = x;
        #pragma unroll
        for (int d = 1; d < 64; d <<= 1) {
            int y = __shfl_up(v, d);
            if (t >= d) v += y;
        }
        bscan[t] = v - x;              // exclusive
    }
    __syncthreads();
    int i = blockIdx.x * 256 + t;
    if (i < E) {
        int d = edge_list[i].x;
        int p = cursor[d] + bscan[d >> 10] + (int)rank[i];
        perm[p] = i;
    }
}

// ---------------- persistent fused MFMA MLP + segment scatter ----------------
// R8/R11 version, byte-for-byte (195us, VGPR 84, 768 blocks, 3/CU).
// LDS map (48 KB):
//   [0,16K)  : B1 frags (W1 hi/lo)   -- persistent
//   [16,32K) : B2 frags (W2 hi/lo)   -- persistent
//   [32,48K) : h1 slices (4 KB/wave) aliased with ACC (64 seg x 64 f32)
// Per-tile: barriers (a) pre-LDS-atomics, (b) pre-flush, (c) post-flush,
// all lgkm-only. Tile T+1's seg scan overlaps tile T's GEMMs.

__global__ __launch_bounds__(256, 3) void edge_mlp_sorted(
    const float* __restrict__ atom,
    const float* __restrict__ edge_emb,
    const unsigned short* __restrict__ wpack,
    const float* __restrict__ b1,
    const float* __restrict__ b2,
    const float* __restrict__ coef,
    const int*   __restrict__ edge_list,       // [E,2]: [dest, src]
    const int*   __restrict__ perm,
    float* __restrict__ num,
    float* __restrict__ den,
    int E)
{
    __shared__ __align__(16) unsigned char SH[49152];
    __shared__ float denacc[TE];
    __shared__ int   segdest[TE];

    unsigned short* B1 = (unsigned short*)SH;            // W1 hi/lo frags
    unsigned short* B2 = (unsigned short*)(SH + 16384);  // W2 hi/lo frags
    float* H1  = (float*)(SH + 32768);                   // h1 slices / ACC
    float* ACC = H1;

    const int t    = threadIdx.x;
    const int w    = t >> 6;
    const int lane = t & 63;
    const int q    = lane >> 4;
    const int n    = lane & 15;
    const int ntiles = (E + TE - 1) / TE;
    const int stride = gridDim.x;

    // ---- one-time: W frags global->LDS, biases->regs, zero ACC/denacc ----
    {
        const uint4* wp = (const uint4*)wpack;
        uint4* shw = (uint4*)SH;
        #pragma unroll
        for (int i = 0; i < 8; ++i)
            shw[t + 256 * i] = wp[t + 256 * i];          // 32 KB
    }
    float b1v[4], b2v[4], cfv[4];
    #pragma unroll
    for (int nt = 0; nt < 4; ++nt) {
        b1v[nt] = b1[nt * 16 + n];
        b2v[nt] = b2[nt * 16 + n];
        cfv[nt] = coef[nt * 16 + n];
    }
    {
        float4 z4 = {0.f, 0.f, 0.f, 0.f};
        float4* az = (float4*)ACC;
        #pragma unroll
        for (int i = 0; i < 4; ++i) az[t + 256 * i] = z4;
        if (t < TE) denacc[t] = 0.f;
    }
    __syncthreads();

    // ---- prime: tile tt0 meta + rows; pA = perm ids of tile tt0+stride ----
    int tt = blockIdx.x;
    int m_head, m_sidx, m_d, m_nseg, m_seg[4], m_src[4];
    int pdnd = -1;
    int pA = 0;
    float4 rA0, rA1, rA2, rA3;
    {
        int eg = tt * TE + lane; if (eg >= E) eg = E - 1;
        int pc = perm[eg];
        int2 pr = ((const int2*)edge_list)[pc];
        int pid = __shfl(pc, w * 16 + n);
        const float* ep = edge_emb + (size_t)pid * HID;
        rA0 = *(const float4*)(ep + q * 8);
        rA1 = *(const float4*)(ep + q * 8 + 4);
        rA2 = *(const float4*)(ep + 32 + q * 8);
        rA3 = *(const float4*)(ep + 36 + q * 8);
        int eb = tt * TE;
        if (lane == 0 && eb > 0)       pdnd = edge_list[2 * perm[eb - 1]];
        if (lane == 63 && eb + TE < E) pdnd = edge_list[2 * perm[eb + TE]];
        tile_scan(pr, lane, w, q, m_head, m_sidx, m_d, m_nseg, m_seg, m_src);
        if (tt + stride < ntiles) {
            int eg2 = (tt + stride) * TE + lane; if (eg2 >= E) eg2 = E - 1;
            pA = perm[eg2];
        }
    }

    for (; tt < ntiles; tt += stride) {
        const int eb = tt * TE;
        const bool hn = (tt + stride) < ntiles;

        // ---- early atom gather (meta known at iter start) ----
        float av[4][4];
        #pragma unroll
        for (int r = 0; r < 4; ++r) {
            const float* ap = atom + (size_t)m_src[r] * HID + n;
            #pragma unroll
            for (int nt = 0; nt < 4; ++nt) av[r][nt] = ap[nt * 16];
        }

        // ---- prefetch tile T+1: pairs, rows, boundary; pB = ids(T+2) ----
        int2 pr_n = make_int2(0, 0);
        float4 rN0 = {0,0,0,0}, rN1 = {0,0,0,0}, rN2 = {0,0,0,0}, rN3 = {0,0,0,0};
        int pB = 0, pdnd_n = -1;
        if (hn) {
            pr_n = ((const int2*)edge_list)[pA];
            int pid2 = __shfl(pA, w * 16 + n);
            const float* ep2 = edge_emb + (size_t)pid2 * HID;
            rN0 = *(const float4*)(ep2 + q * 8);
            rN1 = *(const float4*)(ep2 + q * 8 + 4);
            rN2 = *(const float4*)(ep2 + 32 + q * 8);
            rN3 = *(const float4*)(ep2 + 36 + q * 8);
            int ebn = (tt + stride) * TE;
            if (lane == 0 && ebn > 0)       pdnd_n = edge_list[2 * perm[ebn - 1]];
            if (lane == 63 && ebn + TE < E) pdnd_n = edge_list[2 * perm[ebn + TE]];
            if (tt + 2 * stride < ntiles) {
                int eg3 = (tt + 2 * stride) * TE + lane; if (eg3 >= E) eg3 = E - 1;
                pB = perm[eg3];
            }
        }

        // ---- GEMM1: h1 = tanh(E @ W1 + b1), split-bf16 ----
        short8 a1h[2], a1l[2];
        split8(rA0, rA1, a1h[0], a1l[0]);
        split8(rA2, rA3, a1h[1], a1l[1]);
        float4v c1[4];
        #pragma unroll
        for (int i = 0; i < 4; ++i) c1[i] = (float4v){0.f, 0.f, 0.f, 0.f};
        #pragma unroll
        for (int nt = 0; nt < 4; ++nt) {
            #pragma unroll
            for (int ks = 0; ks < 2; ++ks) {
                int cb = (nt * 2 + ks) * 64 + lane;
                short8 bh = *(const short8*)&B1[cb * 8];
                short8 bl = *(const short8*)&B1[4096 + cb * 8];
                c1[nt] = __builtin_amdgcn_mfma_f32_16x16x32_bf16(a1h[ks], bh, c1[nt], 0, 0, 0);
                c1[nt] = __builtin_amdgcn_mfma_f32_16x16x32_bf16(a1h[ks], bl, c1[nt], 0, 0, 0);
                c1[nt] = __builtin_amdgcn_mfma_f32_16x16x32_bf16(a1l[ks], bh, c1[nt], 0, 0, 0);
            }
        }

        // ---- tile T+1 seg scan: DS latency overlaps the MFMA sections ----
        int nm_head = 0, nm_sidx = 0, nm_d = 0, nm_nseg = 0;
        int nm_seg[4] = {0,0,0,0}, nm_src[4] = {0,0,0,0};
        if (hn)
            tile_scan(pr_n, lane, w, q, nm_head, nm_sidx, nm_d, nm_nseg,
                      nm_seg, nm_src);

        // ---- tanh + h1 write (wave-local slice, swizzled) ----
        float* h1w = H1 + w * 1024;
        #pragma unroll
        for (int nt = 0; nt < 4; ++nt) {
            int f = nt * 16 + n;
            #pragma unroll
            for (int r = 0; r < 4; ++r) {
                int m = q * 4 + r;
                h1w[m * 64 + (f ^ ((m & 7) << 3))] = fast_tanh(c1[nt][r] + b1v[nt]);
            }
        }
        // wave-local fence (reads below are this wave's own slice)
        asm volatile("s_waitcnt lgkmcnt(0)" ::: "memory");
        __builtin_amdgcn_sched_barrier(0);

        // ---- read back as GEMM2 A frags, split to bf16 ----
        short8 a2h[2], a2l[2];
        {
            int m = n;
            #pragma unroll
            for (int ks2 = 0; ks2 < 2; ++ks2) {
                int F0 = (ks2 * 32 + q * 8) ^ ((m & 7) << 3);
                const float* sp = h1w + m * 64 + F0;
                float4 u0 = *(const float4*)&sp[0];
                float4 u1 = *(const float4*)&sp[4];
                split8(u0, u1, a2h[ks2], a2l[ks2]);
            }
        }
        // ---- zero own slice (becomes ACC rows w*16..w*16+15) ----
        {
            float4 z4 = {0.f, 0.f, 0.f, 0.f};
            float* zp = h1w + lane * 16;
            #pragma unroll
            for (int i = 0; i < 4; ++i) *(float4*)(zp + 4 * i) = z4;
        }

        // ---- GEMM2: h2 = h1 @ W2 + b2 ----
        float4v c2[4];
        #pragma unroll
        for (int i = 0; i < 4; ++i) c2[i] = (float4v){0.f, 0.f, 0.f, 0.f};
        #pragma unroll
        for (int nt = 0; nt < 4; ++nt) {
            #pragma unroll
            for (int ks = 0; ks < 2; ++ks) {
                int cb = (nt * 2 + ks) * 64 + lane;
                short8 bh = *(const short8*)&B2[cb * 8];
                short8 bl = *(const short8*)&B2[4096 + cb * 8];
                c2[nt] = __builtin_amdgcn_mfma_f32_16x16x32_bf16(a2h[ks], bh, c2[nt], 0, 0, 0);
                c2[nt] = __builtin_amdgcn_mfma_f32_16x16x32_bf16(a2h[ks], bl, c2[nt], 0, 0, 0);
                c2[nt] = __builtin_amdgcn_mfma_f32_16x16x32_bf16(a2l[ks], bh, c2[nt], 0, 0, 0);
            }
        }

        // ---- msg, attention ----
        float msg[4][4], partial[4], at[4];
        #pragma unroll
        for (int r = 0; r < 4; ++r) {
            float p = 0.f;
            #pragma unroll
            for (int nt = 0; nt < 4; ++nt) {
                float hv = c2[nt][r] + b2v[nt];
                msg[r][nt] = av[r][nt] * hv;
                p = fmaf(msg[r][nt], cfv[nt], p);
            }
            partial[r] = p;
        }
        #pragma unroll
        for (int m = 1; m < 16; m <<= 1) {
            #pragma unroll
            for (int r = 0; r < 4; ++r)
                partial[r] += __shfl_xor(partial[r], m);
        }
        #pragma unroll
        for (int r = 0; r < 4; ++r) {
            int eg = eb + w * 16 + q * 4 + r;
            at[r] = (eg < E) ? __expf(partial[r]) : 0.f;
        }

        bar_lgkm();        // (a) slice-zeros visible; prev flush reads done

        if (m_head) segdest[m_sidx] = m_d;

        // ---- register run-combine over 4 consecutive sorted edges ----
        {
            int curseg = m_seg[0];
            float acc0 = msg[0][0] * at[0], acc1 = msg[0][1] * at[0];
            float acc2 = msg[0][2] * at[0], acc3 = msg[0][3] * at[0];
            float rd = at[0];
            #pragma unroll
            for (int r = 1; r < 4; ++r) {
                if (m_seg[r] == curseg) {
                    acc0 = fmaf(msg[r][0], at[r], acc0);
                    acc1 = fmaf(msg[r][1], at[r], acc1);
                    acc2 = fmaf(msg[r][2], at[r], acc2);
                    acc3 = fmaf(msg[r][3], at[r], acc3);
                    rd += at[r];
                } else {
                    float* p = &ACC[curseg * 64 + n];
                    atomicAdd(p + 0,  acc0); atomicAdd(p + 16, acc1);
                    atomicAdd(p + 32, acc2); atomicAdd(p + 48, acc3);
                    if (n == 0) atomicAdd(&denacc[curseg], rd);
                    curseg = m_seg[r];
                    acc0 = msg[r][0] * at[r]; acc1 = msg[r][1] * at[r];
                    acc2 = msg[r][2] * at[r]; acc3 = msg[r][3] * at[r];
                    rd = at[r];
                }
            }
            float* p = &ACC[curseg * 64 + n];
            atomicAdd(p + 0,  acc0); atomicAdd(p + 16, acc1);
            atomicAdd(p + 32, acc2); atomicAdd(p + 48, acc3);
            if (n == 0) atomicAdd(&denacc[curseg], rd);
        }

        bar_lgkm();        // (b) LDS atomics done

        // ---- flush: interior = stores, boundary = atomics ----
        {
            int prevd = __shfl(pdnd, 0);
            int nextd = __shfl(pdnd, 63);
            int sg = t >> 2;
            int qq = t & 3;
            if (sg < m_nseg) {
                int d2 = segdest[sg];
                bool bnd = (sg == 0 && d2 == prevd) ||
                           (sg == m_nseg - 1 && d2 == nextd);
                float* np = num + (size_t)d2 * HID + qq * 16;
                const float* sp = &ACC[sg * 64 + qq * 16];
                if (bnd) {
                    #pragma unroll
                    for (int j = 0; j < 16; ++j) atomicAdd(np + j, sp[j]);
                    if (qq == 0) { atomicAdd(&den[d2], denacc[sg]); denacc[sg] = 0.f; }
                } else {
                    #pragma unroll
                    for (int j = 0; j < 4; ++j)
                        ((float4*)np)[j] = *(const float4*)(sp + 4 * j);
                    if (qq == 0) { den[d2] = denacc[sg]; denacc[sg] = 0.f; }
                }
            }
        }

        bar_lgkm();        // (c) flush LDS reads done before next h1 write

        if (hn) {
            m_head = nm_head; m_sidx = nm_sidx; m_d = nm_d; m_nseg = nm_nseg;
            #pragma unroll
            for (int r = 0; r < 4; ++r) { m_seg[r] = nm_seg[r]; m_src[r] = nm_src[r]; }
            pdnd = pdnd_n;
            rA0 = rN0; rA1 = rN1; rA2 = rN2; rA3 = rN3;
            pA = pB;
        }
    }
}

__global__ __launch_bounds__(256) void finalize_kernel(
    float* __restrict__ out, const float* __restrict__ den, int n16)
{
    int i = blockIdx.x * blockDim.x + threadIdx.x;
    if (i >= n16) return;
    float d = den[i >> 4];
    if (d > 0.f) {
        float4* p = (float4*)out + i;
        float4 v = *p;
        float r = 1.0f / d;
        v.x *= r; v.y *= r; v.z *= r; v.w *= r;
        *p = v;
    }
}

extern "C" void kernel_launch(void* const* d_in, const int* in_sizes, int n_in,
                              void* d_out, int out_size, void* d_ws, size_t ws_size,
                              hipStream_t stream) {
    const float* atom      = (const float*)d_in[0];
    const float* edge_emb  = (const float*)d_in[1];
    const float* W1        = (const float*)d_in[2];
    const float* b1        = (const float*)d_in[3];
    const float* W2        = (const float*)d_in[4];
    const float* b2        = (const float*)d_in[5];
    const float* coef      = (const float*)d_in[6];
    const int*   edge_list = (const int*)d_in[7];

    const int N = in_sizes[0] / HID;   // 50000
    const int E = in_sizes[1] / HID;   // 800000

    // ws: [den N f32][cursor N i32][blocksums 64][perm E i32]
    //     [rank E u16][wpack 16384 u16]
    float* den       = (float*)d_ws;
    int*   cursor    = (int*)d_ws + N;
    int*   blocksums = (int*)d_ws + 2 * N;
    int*   perm      = (int*)d_ws + 2 * N + 64;
    unsigned short* rank  = (unsigned short*)((int*)d_ws + 2 * N + 64 + E);
    unsigned short* wpack = rank + E;

    // zero den + cursor
    hipMemsetAsync(d_ws, 0, (size_t)(2 * N) * sizeof(int), stream);

    int n4   = N * (HID / 4);                     // float4 count of out
    int eblk = (E + 255) / 256;
    int nb   = (N + 1023) / 1024;                 // 49
    int ghp  = eblk > (n4 + 255) / 256 ? eblk : (n4 + 255) / 256;
    hist_pack<<<ghp, 256, 0, stream>>>((const int2*)edge_list, cursor, rank, E,
                                       W1, W2, wpack, (float4*)d_out, n4);
    scanA_kernel<<<nb, 1024, 0, stream>>>(cursor, blocksums, N);
    perm2_kernel<<<eblk, 256, 0, stream>>>((const int2*)edge_list, cursor,
                                           blocksums, nb, rank, perm, E);

    int ntl  = (E + TE - 1) / TE;
    int nblk = ntl < NBLK_MLP ? ntl : NBLK_MLP;
    edge_mlp_sorted<<<nblk, 256, 0, stream>>>(
        atom, edge_emb, wpack, b1, b2, coef, edge_list, perm,
        (float*)d_out, den, E);

    finalize_kernel<<<(n4 + 255) / 256, 256, 0, stream>>>((float*)d_out, den, n4);
}